// Round 13
// baseline (81.896 us; speedup 1.0000x reference)
//
#include <hip/hip_runtime.h>
#include <math.h>

#define NN 262144
#define PP 64
#define QQ 64
#define TT 2048
#define JJ 512
#define BB 8
#define HH 64

__device__ __forceinline__ float lane_bcast(float v, int l) {
  return __int_as_float(__builtin_amdgcn_readlane(__float_as_int(v), l));
}

// ---------------- kernel 0: segment boundaries (one search per t) -----------
__global__ void k_prep(const int* __restrict__ seg_ids, int* __restrict__ seg_start) {
  int tid = blockIdx.x * blockDim.x + threadIdx.x;
  if (tid <= TT) {
    int lo = 0, hi = NN;
    while (lo < hi) {
      int mid = (lo + hi) >> 1;
      if (seg_ids[mid] < tid) lo = mid + 1; else hi = mid;
    }
    seg_start[tid] = lo;
  }
}

// ------- kernel 1: ew[n][b] = exp( K[n,:] . S[:,idx[b]] ) -------------------
__global__ __launch_bounds__(256) void k_w(const float* __restrict__ Kmat,
                                           const int* __restrict__ idx,
                                           const float* __restrict__ S,
                                           float* __restrict__ ew) {
  __shared__ __align__(16) float s_lds[BB * PP];  // [b][p]
  int tid = threadIdx.x;
  for (int i = tid; i < BB * PP; i += 256) {
    int p = i >> 3, b = i & 7;
    s_lds[b * PP + p] = S[p * JJ + idx[b]];
  }
  __syncthreads();
  int n = blockIdx.x * 64 + (tid >> 2);
  int sub = tid & 3;  // quarter of the K row (16 floats each)
  const float4* Kp = reinterpret_cast<const float4*>(Kmat + (size_t)n * PP + sub * 16);
  float4 kq[4];
#pragma unroll
  for (int j = 0; j < 4; ++j) kq[j] = Kp[j];
  float acc[8];
#pragma unroll
  for (int b = 0; b < 8; ++b) acc[b] = 0.f;
#pragma unroll
  for (int j4 = 0; j4 < 4; ++j4) {
    float4 kk = kq[j4];
#pragma unroll
    for (int b = 0; b < 8; ++b) {
      const float4 sv = *reinterpret_cast<const float4*>(&s_lds[b * PP + sub * 16 + j4 * 4]);
      acc[b] += kk.x * sv.x + kk.y * sv.y + kk.z * sv.z + kk.w * sv.w;
    }
  }
#pragma unroll
  for (int b = 0; b < 8; ++b) {
    acc[b] += __shfl_xor(acc[b], 1);
    acc[b] += __shfl_xor(acc[b], 2);
  }
  float ox = (sub == 0) ? acc[0] : (sub == 1) ? acc[2] : (sub == 2) ? acc[4] : acc[6];
  float oy = (sub == 0) ? acc[1] : (sub == 1) ? acc[3] : (sub == 2) ? acc[5] : acc[7];
  reinterpret_cast<float2*>(ew + (size_t)n * 8)[sub] =
      make_float2(__expf(ox), __expf(oy));
}

// ------- kernel 2: block-per-segment; 8 slice-waves; 2-stage SW pipeline ----
// Named A/B register sets force the compiler to keep two quads' loads in
// flight (the R12 unroll collapsed back to one at VGPR=44). Tail rows are
// predicated (clamped address, x0 weight) so the loop is branch-free.
__global__ __launch_bounds__(512) void k_seg2(const float* __restrict__ ew,
                                              const float* __restrict__ V,
                                              const int* __restrict__ seg_start,
                                              float* __restrict__ M) {
  __shared__ __align__(16) float accred[8][8][64];
  __shared__ float reds[8][8];
  int tid = threadIdx.x;
  int t = blockIdx.x;
  int s = seg_start[t], e = seg_start[t + 1];
  int lane = tid & 63, j = tid >> 6;   // slice 0..7
  int len = e - s;
  int chunk = (len + 7) >> 3;
  int b0 = s + j * chunk;
  int b1 = b0 + chunk; if (b1 > e) b1 = e;
  int slen = (b1 > b0) ? (b1 - b0) : 0;
  int rsub = lane >> 4;       // row within quad
  int qg = lane & 15;         // q columns qg*4 .. +3

  float4 acc[8];
#pragma unroll
  for (int b = 0; b < 8; ++b) acc[b] = make_float4(0.f, 0.f, 0.f, 0.f);
  float4 selo = make_float4(0.f, 0.f, 0.f, 0.f);
  float4 sehi = make_float4(0.f, 0.f, 0.f, 0.f);

#define LOADQ(QI, SET)                                                           \
  {                                                                              \
    int r_ = b0 + (QI) * 4 + rsub;                                               \
    p##SET = (r_ < b1) ? 1.f : 0.f;                                              \
    int rc_ = (r_ < b1) ? r_ : (b1 - 1);                                         \
    const float4* ep_ = reinterpret_cast<const float4*>(ew + (size_t)rc_ * 8);   \
    elo##SET = ep_[0]; ehi##SET = ep_[1];                                        \
    vv##SET = reinterpret_cast<const float4*>(V + (size_t)rc_ * QQ)[qg];         \
  }

#define CONS(SET)                                                                                          \
  {                                                                                                        \
    float4 elo = elo##SET, ehi = ehi##SET, vv = vv##SET;                                                   \
    float pr_ = p##SET;                                                                                    \
    elo.x *= pr_; elo.y *= pr_; elo.z *= pr_; elo.w *= pr_;                                                \
    ehi.x *= pr_; ehi.y *= pr_; ehi.z *= pr_; ehi.w *= pr_;                                                \
    selo.x += elo.x; selo.y += elo.y; selo.z += elo.z; selo.w += elo.w;                                    \
    sehi.x += ehi.x; sehi.y += ehi.y; sehi.z += ehi.z; sehi.w += ehi.w;                                    \
    acc[0].x += elo.x * vv.x; acc[0].y += elo.x * vv.y; acc[0].z += elo.x * vv.z; acc[0].w += elo.x * vv.w; \
    acc[1].x += elo.y * vv.x; acc[1].y += elo.y * vv.y; acc[1].z += elo.y * vv.z; acc[1].w += elo.y * vv.w; \
    acc[2].x += elo.z * vv.x; acc[2].y += elo.z * vv.y; acc[2].z += elo.z * vv.z; acc[2].w += elo.z * vv.w; \
    acc[3].x += elo.w * vv.x; acc[3].y += elo.w * vv.y; acc[3].z += elo.w * vv.z; acc[3].w += elo.w * vv.w; \
    acc[4].x += ehi.x * vv.x; acc[4].y += ehi.x * vv.y; acc[4].z += ehi.x * vv.z; acc[4].w += ehi.x * vv.w; \
    acc[5].x += ehi.y * vv.x; acc[5].y += ehi.y * vv.y; acc[5].z += ehi.y * vv.z; acc[5].w += ehi.y * vv.w; \
    acc[6].x += ehi.z * vv.x; acc[6].y += ehi.z * vv.y; acc[6].z += ehi.z * vv.z; acc[6].w += ehi.z * vv.w; \
    acc[7].x += ehi.w * vv.x; acc[7].y += ehi.w * vv.y; acc[7].z += ehi.w * vv.z; acc[7].w += ehi.w * vv.w; \
  }

  if (slen > 0) {
    int nq = (slen + 3) >> 2;
    float4 eloA, ehiA, vvA, eloB, ehiB, vvB;
    float pA, pB;
    LOADQ(0, A);
    int i = 0;
    for (; i + 2 < nq; i += 2) {
      LOADQ(i + 1, B);
      CONS(A);
      LOADQ(i + 2, A);
      CONS(B);
    }
    if (i + 1 < nq) {
      LOADQ(i + 1, B);
      CONS(A);
      CONS(B);
    } else {
      CONS(A);
    }
  }
#undef LOADQ
#undef CONS

  // reduce across the 4 rsub groups (xor 16, 32 preserve qg)
#pragma unroll
  for (int b = 0; b < 8; ++b) {
    acc[b].x += __shfl_xor(acc[b].x, 16); acc[b].y += __shfl_xor(acc[b].y, 16);
    acc[b].z += __shfl_xor(acc[b].z, 16); acc[b].w += __shfl_xor(acc[b].w, 16);
    acc[b].x += __shfl_xor(acc[b].x, 32); acc[b].y += __shfl_xor(acc[b].y, 32);
    acc[b].z += __shfl_xor(acc[b].z, 32); acc[b].w += __shfl_xor(acc[b].w, 32);
  }
  selo.x += __shfl_xor(selo.x, 16); selo.y += __shfl_xor(selo.y, 16);
  selo.z += __shfl_xor(selo.z, 16); selo.w += __shfl_xor(selo.w, 16);
  sehi.x += __shfl_xor(sehi.x, 16); sehi.y += __shfl_xor(sehi.y, 16);
  sehi.z += __shfl_xor(sehi.z, 16); sehi.w += __shfl_xor(sehi.w, 16);
  selo.x += __shfl_xor(selo.x, 32); selo.y += __shfl_xor(selo.y, 32);
  selo.z += __shfl_xor(selo.z, 32); selo.w += __shfl_xor(selo.w, 32);
  sehi.x += __shfl_xor(sehi.x, 32); sehi.y += __shfl_xor(sehi.y, 32);
  sehi.z += __shfl_xor(sehi.z, 32); sehi.w += __shfl_xor(sehi.w, 32);

  if (rsub == 0) {
#pragma unroll
    for (int b = 0; b < 8; ++b)
      *reinterpret_cast<float4*>(&accred[j][b][qg * 4]) = acc[b];
    if (qg == 0) {
      reds[j][0] = selo.x; reds[j][1] = selo.y; reds[j][2] = selo.z; reds[j][3] = selo.w;
      reds[j][4] = sehi.x; reds[j][5] = sehi.y; reds[j][6] = sehi.z; reds[j][7] = sehi.w;
    }
  }
  __syncthreads();
  {
    int o = tid;
    if (o < 512) {
      int b = o >> 6, q = o & 63;
      float dd = 0.f, sum = 0.f;
#pragma unroll
      for (int jj = 0; jj < 8; ++jj) { dd += reds[jj][b]; sum += accred[jj][b][q]; }
      float inv = (dd > 0.f) ? 1.f / dd : 0.f;
      M[(size_t)t * 512 + o] = sum * inv;   // M[t][b][q]
    }
  }
}

// -------- kernel 3: GI[rho][g] = W_ih[g,:] . X[rho,:] + b_ih  (rho=b*T+t) ---
__global__ __launch_bounds__(256) void k_gi(const float* __restrict__ M,
                                            const float* __restrict__ W_ih,
                                            const float* __restrict__ b_ih,
                                            float* __restrict__ GI) {
  __shared__ float Wt[64 * 193];  // Wt[k*193 + g] = W_ih[g][k]
  int tid = threadIdx.x;
  for (int i = tid; i < 192 * 64; i += 256) {
    int g = i >> 6, k = i & 63;
    Wt[k * 193 + g] = W_ih[i];
  }
  __syncthreads();
  int lane = tid & 63, wv = tid >> 6;
  int row0 = blockIdx.x * 32 + wv * 8;
  float x[8];
#pragma unroll
  for (int rr = 0; rr < 8; ++rr) {
    int rho = row0 + rr;
    int b = rho >> 11, t = rho & 2047;
    x[rr] = M[((size_t)t * 8 + b) * 64 + lane];
  }
  float bi0 = b_ih[lane], bi1 = b_ih[64 + lane], bi2 = b_ih[128 + lane];
  float a0[8], a1[8], a2[8];
#pragma unroll
  for (int rr = 0; rr < 8; ++rr) { a0[rr] = bi0; a1[rr] = bi1; a2[rr] = bi2; }
#pragma unroll
  for (int k = 0; k < 64; ++k) {
    float w0 = Wt[k * 193 + lane];
    float w1 = Wt[k * 193 + 64 + lane];
    float w2 = Wt[k * 193 + 128 + lane];
#pragma unroll
    for (int rr = 0; rr < 8; ++rr) {
      float xk = lane_bcast(x[rr], k);
      a0[rr] += w0 * xk; a1[rr] += w1 * xk; a2[rr] += w2 * xk;
    }
  }
#pragma unroll
  for (int rr = 0; rr < 8; ++rr) {
    size_t rho = (size_t)row0 + rr;
    GI[rho * 192 + lane]       = a0[rr];
    GI[rho * 192 + 64 + lane]  = a1[rr];
    GI[rho * 192 + 128 + lane] = a2[rr];
  }
}

// -------- kernel 4: GRU, one t-row per wave, b128 W reads, padded LDS -------
__global__ __launch_bounds__(256) void k_gru(const float* __restrict__ GI,
                                             const float* __restrict__ W_hh,
                                             const float* __restrict__ b_hh,
                                             const float* __restrict__ w_out,
                                             const float* __restrict__ b_out,
                                             float* __restrict__ preds) {
  __shared__ __align__(16) float Wl[192 * 68];  // row g at g*68, 16 chunks + pad
  int tid = threadIdx.x;
  for (int i = tid; i < 192 * 16; i += 256) {
    int g = i >> 4, c = i & 15;
    *reinterpret_cast<float4*>(&Wl[g * 68 + c * 4]) =
        *reinterpret_cast<const float4*>(W_hh + g * 64 + c * 4);
  }
  __syncthreads();
  int lane = tid & 63, wv = tid >> 6;
  int t = blockIdx.x * 4 + wv;
  float bh0 = b_hh[lane], bh1 = b_hh[64 + lane], bh2 = b_hh[128 + lane];
  float wo = w_out[lane];
  float bo = b_out[0];
  const float* w0base = &Wl[lane * 68];
  const float* w1base = &Wl[(64 + lane) * 68];
  const float* w2base = &Wl[(128 + lane) * 68];

  float gr[8], gz[8], gn[8];
#pragma unroll
  for (int b = 0; b < 8; ++b) {
    size_t base = ((size_t)b * TT + t) * 192;
    gr[b] = GI[base + lane];
    gz[b] = GI[base + 64 + lane];
    gn[b] = GI[base + 128 + lane];
  }

  float h;
  {  // step b=0: h=0 -> gh = b_hh only
    float r = 1.f / (1.f + __expf(-(gr[0] + bh0)));
    float z = 1.f / (1.f + __expf(-(gz[0] + bh1)));
    float nv = tanhf(gn[0] + r * bh2);
    h = (1.f - z) * nv;
    float pv = h * wo;
#pragma unroll
    for (int off = 32; off; off >>= 1) pv += __shfl_xor(pv, off);
    if (lane == 0) preds[t] = pv + bo;
  }
#pragma unroll
  for (int b = 1; b < 8; ++b) {
    float ar = bh0, az = bh1, an = bh2;
#pragma unroll
    for (int c = 0; c < 16; ++c) {
      const float4 w0 = *reinterpret_cast<const float4*>(w0base + c * 4);
      const float4 w1 = *reinterpret_cast<const float4*>(w1base + c * 4);
      const float4 w2 = *reinterpret_cast<const float4*>(w2base + c * 4);
      float a0 = lane_bcast(h, c * 4 + 0), a1 = lane_bcast(h, c * 4 + 1);
      float a2 = lane_bcast(h, c * 4 + 2), a3 = lane_bcast(h, c * 4 + 3);
      ar += w0.x * a0 + w0.y * a1 + w0.z * a2 + w0.w * a3;
      az += w1.x * a0 + w1.y * a1 + w1.z * a2 + w1.w * a3;
      an += w2.x * a0 + w2.y * a1 + w2.z * a2 + w2.w * a3;
    }
    float r = 1.f / (1.f + __expf(-(gr[b] + ar)));
    float z = 1.f / (1.f + __expf(-(gz[b] + az)));
    float nv = tanhf(gn[b] + r * an);
    h = (1.f - z) * nv + z * h;
    float pv = h * wo;
#pragma unroll
    for (int off = 32; off; off >>= 1) pv += __shfl_xor(pv, off);
    if (lane == 0) preds[(size_t)b * TT + t] = pv + bo;
  }
}

extern "C" void kernel_launch(void* const* d_in, const int* in_sizes, int n_in,
                              void* d_out, int out_size, void* d_ws, size_t ws_size,
                              hipStream_t stream) {
  const int*   idx     = (const int*)d_in[0];
  const int*   seg_ids = (const int*)d_in[1];
  const float* Kmat    = (const float*)d_in[2];
  const float* V       = (const float*)d_in[3];
  const float* S       = (const float*)d_in[4];
  const float* W_ih    = (const float*)d_in[5];
  const float* W_hh    = (const float*)d_in[6];
  const float* b_ih    = (const float*)d_in[7];
  const float* b_hh    = (const float*)d_in[8];
  const float* w_out   = (const float*)d_in[9];
  const float* b_out   = (const float*)d_in[10];
  float* out = (float*)d_out;

  char* ws = (char*)d_ws;
  int*   seg_start = (int*)(ws + 0);       // (T+1) ints
  float* ew = (float*)(ws + 8448);         // N*8 f (exp(w))   8.4 MB
  float* M  = (float*)(ws + 8397056);      // T*8*64 f         4.2 MB
  float* GI = (float*)(ws + 12591360);     // 8*T*192 f       12.6 MB

  hipLaunchKernelGGL(k_prep, dim3(9), dim3(256), 0, stream, seg_ids, seg_start);
  hipLaunchKernelGGL(k_w, dim3(NN / 64), dim3(256), 0, stream, Kmat, idx, S, ew);
  hipLaunchKernelGGL(k_seg2, dim3(TT), dim3(512), 0, stream, ew, V, seg_start, M);
  hipLaunchKernelGGL(k_gi, dim3(512), dim3(256), 0, stream, M, W_ih, b_ih, GI);
  hipLaunchKernelGGL(k_gru, dim3(512), dim3(256), 0, stream, GI, W_hh, b_hh, w_out, b_out, out);
}

// Round 14
// 79.081 us; speedup vs baseline: 1.0356x; 1.0356x over previous
//
#include <hip/hip_runtime.h>
#include <math.h>

#define NN 262144
#define PP 64
#define QQ 64
#define TT 2048
#define JJ 512
#define BB 8
#define HH 64

__device__ __forceinline__ float lane_bcast(float v, int l) {
  return __int_as_float(__builtin_amdgcn_readlane(__float_as_int(v), l));
}

// ---------------- kernel 0: segment boundaries (one search per t) -----------
__global__ void k_prep(const int* __restrict__ seg_ids, int* __restrict__ seg_start) {
  int tid = blockIdx.x * blockDim.x + threadIdx.x;
  if (tid <= TT) {
    int lo = 0, hi = NN;
    while (lo < hi) {
      int mid = (lo + hi) >> 1;
      if (seg_ids[mid] < tid) lo = mid + 1; else hi = mid;
    }
    seg_start[tid] = lo;
  }
}

// ------- kernel 1: FUSED per-segment  ew = exp(K.Scols)  ->  sum(ew*V)/sum --
// Block = 1 segment, 4 slice-waves (slice <= 64 rows; P=6 passes covers
// len <= 384, far beyond the ~175 binomial max). Phase K computes each
// slice row's 8 ew values IN REGISTERS (k_w's math: 4 lanes/row, butterfly,
// 2 exps/lane/pass). Phase V streams V float4s and pulls ew via 8 __shfl
// per quad -- no ew global buffer exists at all.
#define NPASS 6
__global__ __launch_bounds__(256) void k_fused2(const float* __restrict__ Kmat,
                                                const int* __restrict__ idx,
                                                const float* __restrict__ S,
                                                const float* __restrict__ V,
                                                const int* __restrict__ seg_start,
                                                float* __restrict__ M) {
  __shared__ __align__(16) float s_cols[BB * PP];   // [b][p]
  __shared__ __align__(16) float accred[4][8][64];
  __shared__ float reds[4][8];
  int tid = threadIdx.x;
  int t = blockIdx.x;
  for (int i = tid; i < BB * PP; i += 256) {
    int p = i >> 3, b = i & 7;
    s_cols[b * PP + p] = S[p * JJ + idx[b]];
  }
  __syncthreads();

  int s = seg_start[t], e = seg_start[t + 1];
  int lane = tid & 63, j = tid >> 6;     // wave j = slice 0..3
  int len = e - s;
  int chunk = (len + 3) >> 2;
  int b0 = s + j * chunk;
  int b1 = b0 + chunk; if (b1 > e) b1 = e;

  // ---- phase K: ew for this wave's rows, in registers ----
  // lane = krow_in*4 + sub ; per pass 16 rows; lane ends with e[2sub],e[2sub+1]
  int krow_in = lane >> 2;
  int sub = lane & 3;
  float ewa[NPASS], ewb[NPASS];
#pragma unroll
  for (int p = 0; p < NPASS; ++p) {
    ewa[p] = 0.f; ewb[p] = 0.f;
    int base = b0 + 16 * p;
    if (base < b1) {                       // wave-uniform
      int rp = base + krow_in;
      int rc = (rp < b1) ? rp : (b1 - 1);
      const float4* Kp = reinterpret_cast<const float4*>(Kmat + (size_t)rc * PP + sub * 16);
      float4 kq[4];
#pragma unroll
      for (int jj = 0; jj < 4; ++jj) kq[jj] = Kp[jj];
      float a8[8];
#pragma unroll
      for (int b = 0; b < 8; ++b) a8[b] = 0.f;
#pragma unroll
      for (int j4 = 0; j4 < 4; ++j4) {
        float4 kk = kq[j4];
#pragma unroll
        for (int b = 0; b < 8; ++b) {
          const float4 sv = *reinterpret_cast<const float4*>(&s_cols[b * PP + sub * 16 + j4 * 4]);
          a8[b] += kk.x * sv.x + kk.y * sv.y + kk.z * sv.z + kk.w * sv.w;
        }
      }
#pragma unroll
      for (int b = 0; b < 8; ++b) {
        a8[b] += __shfl_xor(a8[b], 1);
        a8[b] += __shfl_xor(a8[b], 2);
      }
      float ox = (sub == 0) ? a8[0] : (sub == 1) ? a8[2] : (sub == 2) ? a8[4] : a8[6];
      float oy = (sub == 0) ? a8[1] : (sub == 1) ? a8[3] : (sub == 2) ? a8[5] : a8[7];
      ewa[p] = __expf(ox);
      ewb[p] = __expf(oy);
    }
  }

  // ---- phase V: stream V, pull ew via shuffles ----
  int rsub = lane >> 4;       // row within quad
  int qg = lane & 15;         // q columns qg*4 .. +3
  float4 acc[8];
#pragma unroll
  for (int b = 0; b < 8; ++b) acc[b] = make_float4(0.f, 0.f, 0.f, 0.f);
  float4 selo = make_float4(0.f, 0.f, 0.f, 0.f);
  float4 sehi = make_float4(0.f, 0.f, 0.f, 0.f);

#pragma unroll
  for (int p = 0; p < NPASS; ++p) {
    int base = b0 + 16 * p;
    if (base < b1) {                       // wave-uniform
#pragma unroll
      for (int q = 0; q < 4; ++q) {
        int qb = base + 4 * q;
        if (qb < b1) {                     // wave-uniform
          int r = qb + rsub;
          float pr = (r < b1) ? 1.f : 0.f;
          int rc = (r < b1) ? r : (b1 - 1);
          float4 vv = reinterpret_cast<const float4*>(V + (size_t)rc * QQ)[qg];
          int sL = (4 * q + rsub) * 4;     // source lane base for this row
          float e0 = __shfl(ewa[p], sL + 0), e1 = __shfl(ewb[p], sL + 0);
          float e2 = __shfl(ewa[p], sL + 1), e3 = __shfl(ewb[p], sL + 1);
          float e4 = __shfl(ewa[p], sL + 2), e5 = __shfl(ewb[p], sL + 2);
          float e6 = __shfl(ewa[p], sL + 3), e7 = __shfl(ewb[p], sL + 3);
          e0 *= pr; e1 *= pr; e2 *= pr; e3 *= pr;
          e4 *= pr; e5 *= pr; e6 *= pr; e7 *= pr;
          selo.x += e0; selo.y += e1; selo.z += e2; selo.w += e3;
          sehi.x += e4; sehi.y += e5; sehi.z += e6; sehi.w += e7;
          acc[0].x += e0 * vv.x; acc[0].y += e0 * vv.y; acc[0].z += e0 * vv.z; acc[0].w += e0 * vv.w;
          acc[1].x += e1 * vv.x; acc[1].y += e1 * vv.y; acc[1].z += e1 * vv.z; acc[1].w += e1 * vv.w;
          acc[2].x += e2 * vv.x; acc[2].y += e2 * vv.y; acc[2].z += e2 * vv.z; acc[2].w += e2 * vv.w;
          acc[3].x += e3 * vv.x; acc[3].y += e3 * vv.y; acc[3].z += e3 * vv.z; acc[3].w += e3 * vv.w;
          acc[4].x += e4 * vv.x; acc[4].y += e4 * vv.y; acc[4].z += e4 * vv.z; acc[4].w += e4 * vv.w;
          acc[5].x += e5 * vv.x; acc[5].y += e5 * vv.y; acc[5].z += e5 * vv.z; acc[5].w += e5 * vv.w;
          acc[6].x += e6 * vv.x; acc[6].y += e6 * vv.y; acc[6].z += e6 * vv.z; acc[6].w += e6 * vv.w;
          acc[7].x += e7 * vv.x; acc[7].y += e7 * vv.y; acc[7].z += e7 * vv.z; acc[7].w += e7 * vv.w;
        }
      }
    }
  }

  // ---- reduce across the 4 rsub groups (xor 16, 32 preserve qg) ----
#pragma unroll
  for (int b = 0; b < 8; ++b) {
    acc[b].x += __shfl_xor(acc[b].x, 16); acc[b].y += __shfl_xor(acc[b].y, 16);
    acc[b].z += __shfl_xor(acc[b].z, 16); acc[b].w += __shfl_xor(acc[b].w, 16);
    acc[b].x += __shfl_xor(acc[b].x, 32); acc[b].y += __shfl_xor(acc[b].y, 32);
    acc[b].z += __shfl_xor(acc[b].z, 32); acc[b].w += __shfl_xor(acc[b].w, 32);
  }
  selo.x += __shfl_xor(selo.x, 16); selo.y += __shfl_xor(selo.y, 16);
  selo.z += __shfl_xor(selo.z, 16); selo.w += __shfl_xor(selo.w, 16);
  sehi.x += __shfl_xor(sehi.x, 16); sehi.y += __shfl_xor(sehi.y, 16);
  sehi.z += __shfl_xor(sehi.z, 16); sehi.w += __shfl_xor(sehi.w, 16);
  selo.x += __shfl_xor(selo.x, 32); selo.y += __shfl_xor(selo.y, 32);
  selo.z += __shfl_xor(selo.z, 32); selo.w += __shfl_xor(selo.w, 32);
  sehi.x += __shfl_xor(sehi.x, 32); sehi.y += __shfl_xor(sehi.y, 32);
  sehi.z += __shfl_xor(sehi.z, 32); sehi.w += __shfl_xor(sehi.w, 32);

  if (rsub == 0) {
#pragma unroll
    for (int b = 0; b < 8; ++b)
      *reinterpret_cast<float4*>(&accred[j][b][qg * 4]) = acc[b];
    if (qg == 0) {
      reds[j][0] = selo.x; reds[j][1] = selo.y; reds[j][2] = selo.z; reds[j][3] = selo.w;
      reds[j][4] = sehi.x; reds[j][5] = sehi.y; reds[j][6] = sehi.z; reds[j][7] = sehi.w;
    }
  }
  __syncthreads();
  for (int o = tid; o < 512; o += 256) {
    int b = o >> 6, q = o & 63;
    float dd = reds[0][b] + reds[1][b] + reds[2][b] + reds[3][b];
    float inv = (dd > 0.f) ? 1.f / dd : 0.f;
    float sum = accred[0][b][q] + accred[1][b][q] + accred[2][b][q] + accred[3][b][q];
    M[(size_t)t * 512 + o] = sum * inv;   // M[t][b][q]
  }
}

// -------- kernel 2: GI[rho][g] = W_ih[g,:] . X[rho,:] + b_ih  (rho=b*T+t) ---
__global__ __launch_bounds__(256) void k_gi(const float* __restrict__ M,
                                            const float* __restrict__ W_ih,
                                            const float* __restrict__ b_ih,
                                            float* __restrict__ GI) {
  __shared__ float Wt[64 * 193];  // Wt[k*193 + g] = W_ih[g][k]
  int tid = threadIdx.x;
  for (int i = tid; i < 192 * 64; i += 256) {
    int g = i >> 6, k = i & 63;
    Wt[k * 193 + g] = W_ih[i];
  }
  __syncthreads();
  int lane = tid & 63, wv = tid >> 6;
  int row0 = blockIdx.x * 32 + wv * 8;
  float x[8];
#pragma unroll
  for (int rr = 0; rr < 8; ++rr) {
    int rho = row0 + rr;
    int b = rho >> 11, t = rho & 2047;
    x[rr] = M[((size_t)t * 8 + b) * 64 + lane];
  }
  float bi0 = b_ih[lane], bi1 = b_ih[64 + lane], bi2 = b_ih[128 + lane];
  float a0[8], a1[8], a2[8];
#pragma unroll
  for (int rr = 0; rr < 8; ++rr) { a0[rr] = bi0; a1[rr] = bi1; a2[rr] = bi2; }
#pragma unroll
  for (int k = 0; k < 64; ++k) {
    float w0 = Wt[k * 193 + lane];
    float w1 = Wt[k * 193 + 64 + lane];
    float w2 = Wt[k * 193 + 128 + lane];
#pragma unroll
    for (int rr = 0; rr < 8; ++rr) {
      float xk = lane_bcast(x[rr], k);
      a0[rr] += w0 * xk; a1[rr] += w1 * xk; a2[rr] += w2 * xk;
    }
  }
#pragma unroll
  for (int rr = 0; rr < 8; ++rr) {
    size_t rho = (size_t)row0 + rr;
    GI[rho * 192 + lane]       = a0[rr];
    GI[rho * 192 + 64 + lane]  = a1[rr];
    GI[rho * 192 + 128 + lane] = a2[rr];
  }
}

// -------- kernel 3: GRU, one t-row per wave, b128 W reads, padded LDS -------
__global__ __launch_bounds__(256) void k_gru(const float* __restrict__ GI,
                                             const float* __restrict__ W_hh,
                                             const float* __restrict__ b_hh,
                                             const float* __restrict__ w_out,
                                             const float* __restrict__ b_out,
                                             float* __restrict__ preds) {
  __shared__ __align__(16) float Wl[192 * 68];  // row g at g*68, 16 chunks + pad
  int tid = threadIdx.x;
  for (int i = tid; i < 192 * 16; i += 256) {
    int g = i >> 4, c = i & 15;
    *reinterpret_cast<float4*>(&Wl[g * 68 + c * 4]) =
        *reinterpret_cast<const float4*>(W_hh + g * 64 + c * 4);
  }
  __syncthreads();
  int lane = tid & 63, wv = tid >> 6;
  int t = blockIdx.x * 4 + wv;
  float bh0 = b_hh[lane], bh1 = b_hh[64 + lane], bh2 = b_hh[128 + lane];
  float wo = w_out[lane];
  float bo = b_out[0];
  const float* w0base = &Wl[lane * 68];
  const float* w1base = &Wl[(64 + lane) * 68];
  const float* w2base = &Wl[(128 + lane) * 68];

  float gr[8], gz[8], gn[8];
#pragma unroll
  for (int b = 0; b < 8; ++b) {
    size_t base = ((size_t)b * TT + t) * 192;
    gr[b] = GI[base + lane];
    gz[b] = GI[base + 64 + lane];
    gn[b] = GI[base + 128 + lane];
  }

  float h;
  {  // step b=0: h=0 -> gh = b_hh only
    float r = 1.f / (1.f + __expf(-(gr[0] + bh0)));
    float z = 1.f / (1.f + __expf(-(gz[0] + bh1)));
    float nv = tanhf(gn[0] + r * bh2);
    h = (1.f - z) * nv;
    float pv = h * wo;
#pragma unroll
    for (int off = 32; off; off >>= 1) pv += __shfl_xor(pv, off);
    if (lane == 0) preds[t] = pv + bo;
  }
#pragma unroll
  for (int b = 1; b < 8; ++b) {
    float ar = bh0, az = bh1, an = bh2;
#pragma unroll
    for (int c = 0; c < 16; ++c) {
      const float4 w0 = *reinterpret_cast<const float4*>(w0base + c * 4);
      const float4 w1 = *reinterpret_cast<const float4*>(w1base + c * 4);
      const float4 w2 = *reinterpret_cast<const float4*>(w2base + c * 4);
      float a0 = lane_bcast(h, c * 4 + 0), a1 = lane_bcast(h, c * 4 + 1);
      float a2 = lane_bcast(h, c * 4 + 2), a3 = lane_bcast(h, c * 4 + 3);
      ar += w0.x * a0 + w0.y * a1 + w0.z * a2 + w0.w * a3;
      az += w1.x * a0 + w1.y * a1 + w1.z * a2 + w1.w * a3;
      an += w2.x * a0 + w2.y * a1 + w2.z * a2 + w2.w * a3;
    }
    float r = 1.f / (1.f + __expf(-(gr[b] + ar)));
    float z = 1.f / (1.f + __expf(-(gz[b] + az)));
    float nv = tanhf(gn[b] + r * an);
    h = (1.f - z) * nv + z * h;
    float pv = h * wo;
#pragma unroll
    for (int off = 32; off; off >>= 1) pv += __shfl_xor(pv, off);
    if (lane == 0) preds[(size_t)b * TT + t] = pv + bo;
  }
}

extern "C" void kernel_launch(void* const* d_in, const int* in_sizes, int n_in,
                              void* d_out, int out_size, void* d_ws, size_t ws_size,
                              hipStream_t stream) {
  const int*   idx     = (const int*)d_in[0];
  const int*   seg_ids = (const int*)d_in[1];
  const float* Kmat    = (const float*)d_in[2];
  const float* V       = (const float*)d_in[3];
  const float* S       = (const float*)d_in[4];
  const float* W_ih    = (const float*)d_in[5];
  const float* W_hh    = (const float*)d_in[6];
  const float* b_ih    = (const float*)d_in[7];
  const float* b_hh    = (const float*)d_in[8];
  const float* w_out   = (const float*)d_in[9];
  const float* b_out   = (const float*)d_in[10];
  float* out = (float*)d_out;

  char* ws = (char*)d_ws;
  int*   seg_start = (int*)(ws + 0);       // (T+1) ints
  float* M  = (float*)(ws + 8448);         // T*8*64 f   4.2 MB
  float* GI = (float*)(ws + 4202752);      // 8*T*192 f  12.6 MB

  hipLaunchKernelGGL(k_prep, dim3(9), dim3(256), 0, stream, seg_ids, seg_start);
  hipLaunchKernelGGL(k_fused2, dim3(TT), dim3(256), 0, stream,
                     Kmat, idx, S, V, seg_start, M);
  hipLaunchKernelGGL(k_gi, dim3(512), dim3(256), 0, stream, M, W_ih, b_ih, GI);
  hipLaunchKernelGGL(k_gru, dim3(512), dim3(256), 0, stream, GI, W_hh, b_hh, w_out, b_out, out);
}

// Round 15
// 75.521 us; speedup vs baseline: 1.0844x; 1.0471x over previous
//
#include <hip/hip_runtime.h>
#include <math.h>

#define NN 262144
#define PP 64
#define QQ 64
#define TT 2048
#define JJ 512
#define BB 8
#define HH 64
#define PSTRIDE 520

__device__ __forceinline__ float lane_bcast(float v, int l) {
  return __int_as_float(__builtin_amdgcn_readlane(__float_as_int(v), l));
}

// ------- kernel 1: ew = exp(K.Scols); blocks 0-8 also compute seg_start -----
__global__ __launch_bounds__(256) void k_wp(const float* __restrict__ Kmat,
                                            const int* __restrict__ idx,
                                            const float* __restrict__ S,
                                            const int* __restrict__ seg_ids,
                                            float* __restrict__ ew,
                                            int* __restrict__ seg_start) {
  int tid = threadIdx.x;
  int gtid = blockIdx.x * 256 + tid;
  if (gtid <= TT) {   // folded k_prep: 2049 searches in blocks 0..8
    int lo = 0, hi = NN;
    while (lo < hi) {
      int mid = (lo + hi) >> 1;
      if (seg_ids[mid] < gtid) lo = mid + 1; else hi = mid;
    }
    seg_start[gtid] = lo;
  }
  __shared__ __align__(16) float s_lds[BB * PP];  // [b][p]
  for (int i = tid; i < BB * PP; i += 256) {
    int p = i >> 3, b = i & 7;
    s_lds[b * PP + p] = S[p * JJ + idx[b]];
  }
  __syncthreads();
  int n = blockIdx.x * 64 + (tid >> 2);
  int sub = tid & 3;  // quarter of the K row (16 floats each)
  const float4* Kp = reinterpret_cast<const float4*>(Kmat + (size_t)n * PP + sub * 16);
  float4 kq[4];
#pragma unroll
  for (int j = 0; j < 4; ++j) kq[j] = Kp[j];
  float acc[8];
#pragma unroll
  for (int b = 0; b < 8; ++b) acc[b] = 0.f;
#pragma unroll
  for (int j4 = 0; j4 < 4; ++j4) {
    float4 kk = kq[j4];
#pragma unroll
    for (int b = 0; b < 8; ++b) {
      const float4 sv = *reinterpret_cast<const float4*>(&s_lds[b * PP + sub * 16 + j4 * 4]);
      acc[b] += kk.x * sv.x + kk.y * sv.y + kk.z * sv.z + kk.w * sv.w;
    }
  }
#pragma unroll
  for (int b = 0; b < 8; ++b) {
    acc[b] += __shfl_xor(acc[b], 1);
    acc[b] += __shfl_xor(acc[b], 2);
  }
  float ox = (sub == 0) ? acc[0] : (sub == 1) ? acc[2] : (sub == 2) ? acc[4] : acc[6];
  float oy = (sub == 0) ? acc[1] : (sub == 1) ? acc[3] : (sub == 2) ? acc[5] : acc[7];
  reinterpret_cast<float2*>(ew + (size_t)n * 8)[sub] =
      make_float2(__expf(ox), __expf(oy));
}

// ------- kernel 2: partial segment sums, 4 slice-waves per segment (R7) -----
__global__ __launch_bounds__(256) void k_segp(const float* __restrict__ ew,
                                              const float* __restrict__ V,
                                              const int* __restrict__ seg_start,
                                              float* __restrict__ P) {
  int lane = threadIdx.x & 63, j = threadIdx.x >> 6;
  int t = blockIdx.x;
  int s = seg_start[t], e = seg_start[t + 1];
  int len = e - s;
  int chunk = (len + 3) >> 2;
  int b0 = s + j * chunk;
  int b1 = b0 + chunk; if (b1 > e) b1 = e;
  int slen = (b1 > b0) ? (b1 - b0) : 0;
  int rsub = lane >> 4;       // which of 4 rows in the quad
  int qg = lane & 15;         // q block: columns qg*4 .. qg*4+3

  float4 acc[8];
#pragma unroll
  for (int b = 0; b < 8; ++b) acc[b] = make_float4(0.f, 0.f, 0.f, 0.f);
  float4 selo = make_float4(0.f, 0.f, 0.f, 0.f);
  float4 sehi = make_float4(0.f, 0.f, 0.f, 0.f);

#define PROC(RR)                                                                                           \
  {                                                                                                        \
    int r_ = (RR);                                                                                         \
    const float4* ewp_ = reinterpret_cast<const float4*>(ew + (size_t)r_ * 8);                             \
    float4 elo = ewp_[0], ehi = ewp_[1];                                                                   \
    float4 vv = reinterpret_cast<const float4*>(V + (size_t)r_ * QQ)[qg];                                  \
    selo.x += elo.x; selo.y += elo.y; selo.z += elo.z; selo.w += elo.w;                                    \
    sehi.x += ehi.x; sehi.y += ehi.y; sehi.z += ehi.z; sehi.w += ehi.w;                                    \
    acc[0].x += elo.x * vv.x; acc[0].y += elo.x * vv.y; acc[0].z += elo.x * vv.z; acc[0].w += elo.x * vv.w; \
    acc[1].x += elo.y * vv.x; acc[1].y += elo.y * vv.y; acc[1].z += elo.y * vv.z; acc[1].w += elo.y * vv.w; \
    acc[2].x += elo.z * vv.x; acc[2].y += elo.z * vv.y; acc[2].z += elo.z * vv.z; acc[2].w += elo.z * vv.w; \
    acc[3].x += elo.w * vv.x; acc[3].y += elo.w * vv.y; acc[3].z += elo.w * vv.z; acc[3].w += elo.w * vv.w; \
    acc[4].x += ehi.x * vv.x; acc[4].y += ehi.x * vv.y; acc[4].z += ehi.x * vv.z; acc[4].w += ehi.x * vv.w; \
    acc[5].x += ehi.y * vv.x; acc[5].y += ehi.y * vv.y; acc[5].z += ehi.y * vv.z; acc[5].w += ehi.y * vv.w; \
    acc[6].x += ehi.z * vv.x; acc[6].y += ehi.z * vv.y; acc[6].z += ehi.z * vv.z; acc[6].w += ehi.z * vv.w; \
    acc[7].x += ehi.w * vv.x; acc[7].y += ehi.w * vv.y; acc[7].z += ehi.w * vv.z; acc[7].w += ehi.w * vv.w; \
  }

  int nfull = slen >> 2, tail = slen & 3;
  for (int i = 0; i < nfull; ++i) PROC(b0 + i * 4 + rsub);
  if (tail && rsub < tail) PROC(b0 + nfull * 4 + rsub);
#undef PROC

#pragma unroll
  for (int b = 0; b < 8; ++b) {
    acc[b].x += __shfl_xor(acc[b].x, 16); acc[b].y += __shfl_xor(acc[b].y, 16);
    acc[b].z += __shfl_xor(acc[b].z, 16); acc[b].w += __shfl_xor(acc[b].w, 16);
    acc[b].x += __shfl_xor(acc[b].x, 32); acc[b].y += __shfl_xor(acc[b].y, 32);
    acc[b].z += __shfl_xor(acc[b].z, 32); acc[b].w += __shfl_xor(acc[b].w, 32);
  }
  selo.x += __shfl_xor(selo.x, 16); selo.y += __shfl_xor(selo.y, 16);
  selo.z += __shfl_xor(selo.z, 16); selo.w += __shfl_xor(selo.w, 16);
  sehi.x += __shfl_xor(sehi.x, 16); sehi.y += __shfl_xor(sehi.y, 16);
  sehi.z += __shfl_xor(sehi.z, 16); sehi.w += __shfl_xor(sehi.w, 16);
  selo.x += __shfl_xor(selo.x, 32); selo.y += __shfl_xor(selo.y, 32);
  selo.z += __shfl_xor(selo.z, 32); selo.w += __shfl_xor(selo.w, 32);
  sehi.x += __shfl_xor(sehi.x, 32); sehi.y += __shfl_xor(sehi.y, 32);
  sehi.z += __shfl_xor(sehi.z, 32); sehi.w += __shfl_xor(sehi.w, 32);

  float* Pp = P + ((size_t)t * 4 + j) * PSTRIDE;
  if (rsub == 0) {
#pragma unroll
    for (int b = 0; b < 8; ++b)
      *reinterpret_cast<float4*>(Pp + b * 64 + qg * 4) = acc[b];
    if (qg == 0) {
      Pp[512] = selo.x; Pp[513] = selo.y; Pp[514] = selo.z; Pp[515] = selo.w;
      Pp[516] = sehi.x; Pp[517] = sehi.y; Pp[518] = sehi.z; Pp[519] = sehi.w;
    }
  }
}

// -------- kernel 3: GI = W_ih . X + b_ih, reduce+normalize fused ------------
__global__ __launch_bounds__(256) void k_gir(const float* __restrict__ P,
                                             const float* __restrict__ W_ih,
                                             const float* __restrict__ b_ih,
                                             float* __restrict__ GI) {
  __shared__ float Wt[64 * 193];  // Wt[k*193 + g] = W_ih[g][k]
  int tid = threadIdx.x;
  for (int i = tid; i < 192 * 64; i += 256) {
    int g = i >> 6, k = i & 63;
    Wt[k * 193 + g] = W_ih[i];
  }
  __syncthreads();
  int lane = tid & 63, wv = tid >> 6;
  int row0 = blockIdx.x * 32 + wv * 8;
  float x[8];
#pragma unroll
  for (int rr = 0; rr < 8; ++rr) {
    int rho = row0 + rr;
    int b = rho >> 11, t = rho & 2047;
    const float* P0 = P + (size_t)t * 4 * PSTRIDE;
    float dd = P0[512 + b] + P0[PSTRIDE + 512 + b] +
               P0[2 * PSTRIDE + 512 + b] + P0[3 * PSTRIDE + 512 + b];
    float inv = (dd > 0.f) ? 1.f / dd : 0.f;
    float sum = P0[b * 64 + lane] + P0[PSTRIDE + b * 64 + lane] +
                P0[2 * PSTRIDE + b * 64 + lane] + P0[3 * PSTRIDE + b * 64 + lane];
    x[rr] = sum * inv;
  }
  float bi0 = b_ih[lane], bi1 = b_ih[64 + lane], bi2 = b_ih[128 + lane];
  float a0[8], a1[8], a2[8];
#pragma unroll
  for (int rr = 0; rr < 8; ++rr) { a0[rr] = bi0; a1[rr] = bi1; a2[rr] = bi2; }
#pragma unroll
  for (int k = 0; k < 64; ++k) {
    float w0 = Wt[k * 193 + lane];
    float w1 = Wt[k * 193 + 64 + lane];
    float w2 = Wt[k * 193 + 128 + lane];
#pragma unroll
    for (int rr = 0; rr < 8; ++rr) {
      float xk = lane_bcast(x[rr], k);
      a0[rr] += w0 * xk; a1[rr] += w1 * xk; a2[rr] += w2 * xk;
    }
  }
#pragma unroll
  for (int rr = 0; rr < 8; ++rr) {
    size_t rho = (size_t)row0 + rr;
    GI[rho * 192 + lane]       = a0[rr];
    GI[rho * 192 + 64 + lane]  = a1[rr];
    GI[rho * 192 + 128 + lane] = a2[rr];
  }
}

// -------- kernel 4: GRU, one t-row per wave, b128 W reads, padded LDS -------
__global__ __launch_bounds__(256) void k_gru(const float* __restrict__ GI,
                                             const float* __restrict__ W_hh,
                                             const float* __restrict__ b_hh,
                                             const float* __restrict__ w_out,
                                             const float* __restrict__ b_out,
                                             float* __restrict__ preds) {
  __shared__ __align__(16) float Wl[192 * 68];  // row g at g*68, 16 chunks + pad
  int tid = threadIdx.x;
  for (int i = tid; i < 192 * 16; i += 256) {
    int g = i >> 4, c = i & 15;
    *reinterpret_cast<float4*>(&Wl[g * 68 + c * 4]) =
        *reinterpret_cast<const float4*>(W_hh + g * 64 + c * 4);
  }
  __syncthreads();
  int lane = tid & 63, wv = tid >> 6;
  int t = blockIdx.x * 4 + wv;
  float bh0 = b_hh[lane], bh1 = b_hh[64 + lane], bh2 = b_hh[128 + lane];
  float wo = w_out[lane];
  float bo = b_out[0];
  const float* w0base = &Wl[lane * 68];
  const float* w1base = &Wl[(64 + lane) * 68];
  const float* w2base = &Wl[(128 + lane) * 68];

  float gr[8], gz[8], gn[8];
#pragma unroll
  for (int b = 0; b < 8; ++b) {
    size_t base = ((size_t)b * TT + t) * 192;
    gr[b] = GI[base + lane];
    gz[b] = GI[base + 64 + lane];
    gn[b] = GI[base + 128 + lane];
  }

  float h;
  {  // step b=0: h=0 -> gh = b_hh only
    float r = 1.f / (1.f + __expf(-(gr[0] + bh0)));
    float z = 1.f / (1.f + __expf(-(gz[0] + bh1)));
    float nv = tanhf(gn[0] + r * bh2);
    h = (1.f - z) * nv;
    float pv = h * wo;
#pragma unroll
    for (int off = 32; off; off >>= 1) pv += __shfl_xor(pv, off);
    if (lane == 0) preds[t] = pv + bo;
  }
#pragma unroll
  for (int b = 1; b < 8; ++b) {
    float ar = bh0, az = bh1, an = bh2;
#pragma unroll
    for (int c = 0; c < 16; ++c) {
      const float4 w0 = *reinterpret_cast<const float4*>(w0base + c * 4);
      const float4 w1 = *reinterpret_cast<const float4*>(w1base + c * 4);
      const float4 w2 = *reinterpret_cast<const float4*>(w2base + c * 4);
      float a0 = lane_bcast(h, c * 4 + 0), a1 = lane_bcast(h, c * 4 + 1);
      float a2 = lane_bcast(h, c * 4 + 2), a3 = lane_bcast(h, c * 4 + 3);
      ar += w0.x * a0 + w0.y * a1 + w0.z * a2 + w0.w * a3;
      az += w1.x * a0 + w1.y * a1 + w1.z * a2 + w1.w * a3;
      an += w2.x * a0 + w2.y * a1 + w2.z * a2 + w2.w * a3;
    }
    float r = 1.f / (1.f + __expf(-(gr[b] + ar)));
    float z = 1.f / (1.f + __expf(-(gz[b] + az)));
    float nv = tanhf(gn[b] + r * an);
    h = (1.f - z) * nv + z * h;
    float pv = h * wo;
#pragma unroll
    for (int off = 32; off; off >>= 1) pv += __shfl_xor(pv, off);
    if (lane == 0) preds[(size_t)b * TT + t] = pv + bo;
  }
}

extern "C" void kernel_launch(void* const* d_in, const int* in_sizes, int n_in,
                              void* d_out, int out_size, void* d_ws, size_t ws_size,
                              hipStream_t stream) {
  const int*   idx     = (const int*)d_in[0];
  const int*   seg_ids = (const int*)d_in[1];
  const float* Kmat    = (const float*)d_in[2];
  const float* V       = (const float*)d_in[3];
  const float* S       = (const float*)d_in[4];
  const float* W_ih    = (const float*)d_in[5];
  const float* W_hh    = (const float*)d_in[6];
  const float* b_ih    = (const float*)d_in[7];
  const float* b_hh    = (const float*)d_in[8];
  const float* w_out   = (const float*)d_in[9];
  const float* b_out   = (const float*)d_in[10];
  float* out = (float*)d_out;

  char* ws = (char*)d_ws;
  int*   seg_start = (int*)(ws + 0);       // (T+1) ints
  float* ew = (float*)(ws + 8448);         // N*8 f        8.4 MB
  float* P  = (float*)(ws + 8397056);      // T*4*520 f   17.0 MB
  float* GI = (float*)(ws + 25434112);     // 8*T*192 f   12.6 MB

  hipLaunchKernelGGL(k_wp, dim3(NN / 64), dim3(256), 0, stream,
                     Kmat, idx, S, seg_ids, ew, seg_start);
  hipLaunchKernelGGL(k_segp, dim3(TT), dim3(256), 0, stream, ew, V, seg_start, P);
  hipLaunchKernelGGL(k_gir, dim3(512), dim3(256), 0, stream, P, W_ih, b_ih, GI);
  hipLaunchKernelGGL(k_gru, dim3(512), dim3(256), 0, stream, GI, W_hh, b_hh, w_out, b_out, out);
}